// Round 3
// baseline (415.866 us; speedup 1.0000x reference)
//
#include <hip/hip_runtime.h>
#include <hip/hip_cooperative_groups.h>
#include <math.h>

namespace cg = cooperative_groups;

// Model: B=32, C=64, T=1024, H=10, OUT=2.
// Primary path: ONE cooperative kernel (S1 embed / S2 bn+tanh+qkv / S3 act+M /
// S4 N, prec / S5 bn+relu+Iin+g) with activations held in REGISTERS across
// grid.sync(), then a separate LDS-staged LSNN scan kernel.
// Fallback path (if cooperative launch is rejected): the round-1 9-kernel
// pipeline (verified absmax 0.0), feeding the same scan kernel.

constexpr int B = 32, C = 64, T = 1024, H = 10;
constexpr int BHT = B * H * T;        // 327680
constexpr int NB = 256, NT = 128;     // coop grid: one thread per (b,t)

// ---- workspace float offsets ----
// shared by both paths:
constexpr size_t OFF_IIN = 327680;    // Iin stride-10: 327,680 floats
constexpr size_t OFF_G   = 1651360;   // g[1024]
// coop-only (overlaps fallback's pre1 region; only one path runs per call):
constexpr size_t OFF_CMP = 0;         // 256*100 M partials
constexpr size_t OFF_CP1 = 25600;     // 256*20
constexpr size_t OFF_CP2 = 30720;     // 256*60
constexpr size_t OFF_CP3 = 46080;     // 256*20
// fallback-only (round-1 layout):
constexpr size_t OFF_PRE1 = 0;
constexpr size_t OFF_PREQ = 327680;   // preq; Iin overwrites it later (same region)
constexpr size_t OFF_PREK = 655360;
constexpr size_t OFF_PREV = 983040;
constexpr size_t OFF_Q    = 1310720;
constexpr size_t OFF_ST1  = 1638400;
constexpr size_t OFF_STQ  = 1638432;
constexpr size_t OFF_STK  = 1638464;
constexpr size_t OFF_STV  = 1638496;
constexpr size_t OFF_STC  = 1638528;
constexpr size_t OFF_MPF  = 1638560;  // 32*4*100

struct Params {
  const float *beeg, *W_ef, *b_ef, *g_i, *be_i, *Wq, *g_q, *be_q, *Wk, *g_k,
      *be_k, *Wv, *g_v, *be_v, *Wc, *g_c, *be_c, *W_in;
  float *Iin, *g, *Mpart, *P1, *P2, *P3;
};

__device__ inline float wred(float v) {
#pragma unroll
  for (int o = 32; o; o >>= 1) v += __shfl_down(v, o, 64);
  return v;
}

__device__ inline void write_iin(float* __restrict__ Iin, int b, int t,
                                 const float* Ii) {
  float2* o2 = (float2*)(Iin + (size_t)((b << 10) | t) * 10);  // 8B aligned
  o2[0] = make_float2(Ii[0], Ii[1]);
  o2[1] = make_float2(Ii[2], Ii[3]);
  o2[2] = make_float2(Ii[4], Ii[5]);
  o2[3] = make_float2(Ii[6], Ii[7]);
  o2[4] = make_float2(Ii[8], Ii[9]);
}

__device__ inline void write_g(float* __restrict__ g, int gid) {
  if (gid < T) {
    const double a_ = 0.9, d_ = 0.8, c_ = 0.1;
    int Mi = T - 1 - gid;
    double Ga = a_ * (1.0 - pow(a_, (double)(Mi + 1))) / (1.0 - a_);
    double Gd = d_ * (1.0 - pow(d_, (double)(Mi + 1))) / (1.0 - d_);
    g[gid] = (float)(c_ * (Ga - Gd) / (a_ - d_) / (double)T);
  }
}

// ======================= cooperative fused kernel =======================
// cross-block stats reduce: P is [256][2*nch] f32 partials (sums, then sumsqs)
__device__ inline void xreduce(const float* __restrict__ P, int nch,
                               double* dred, double* dtot, float* stM,
                               float* stI, int tid) {
  const int Q = 2 * nch;
  for (int it = tid; it < Q * 8; it += NT) {
    int c = it >> 3, ch = it & 7;
    double s = 0.0;
    const float* base = P + (size_t)(ch * 32) * Q + c;
    for (int i = 0; i < 32; ++i) s += (double)base[(size_t)i * Q];
    dred[it] = s;
  }
  __syncthreads();
  if (tid < Q) {
    double s = 0.0;
#pragma unroll
    for (int i = 0; i < 8; ++i) s += dred[tid * 8 + i];
    dtot[tid] = s;
  }
  __syncthreads();
  if (tid < nch) {
    double mean = dtot[tid] * (1.0 / 32768.0);
    double var  = dtot[nch + tid] * (1.0 / 32768.0) - mean * mean;
    stM[tid] = (float)mean;
    stI[tid] = (float)(1.0 / sqrt(var + 1e-5));
  }
  __syncthreads();
}

__global__ __launch_bounds__(NT) void fused(Params p) {
  const int k = blockIdx.x, tid = threadIdx.x;
  const int b = k >> 3, t = ((k & 7) << 7) | tid;
  const int lane = tid & 63, wid = tid >> 6;
  cg::grid_group grid = cg::this_grid();

  __shared__ float sredf[2][100];
  __shared__ double dred[480], dtot[60];
  __shared__ float stM[30], stI[30];
  __shared__ float Ms[100], Nl[100];

  // S1: embed (coalesced: consecutive lanes -> consecutive t)
  float pre1[H];
#pragma unroll
  for (int h = 0; h < H; ++h) pre1[h] = p.b_ef[h];
  {
    const float* bp = p.beeg + (size_t)b * C * T + t;
    for (int c = 0; c < C; ++c) {
      float x = bp[(size_t)c * T];
#pragma unroll
      for (int h = 0; h < H; ++h) pre1[h] = fmaf(x, p.W_ef[h * C + c], pre1[h]);
    }
  }
#pragma unroll
  for (int h = 0; h < H; ++h) {
    float r1 = wred(pre1[h]), r2 = wred(pre1[h] * pre1[h]);
    if (lane == 0) { sredf[wid][h] = r1; sredf[wid][10 + h] = r2; }
  }
  __syncthreads();
  if (tid < 20) p.P1[(size_t)k * 20 + tid] = sredf[0][tid] + sredf[1][tid];
  grid.sync();

  // S2: bn+tanh, q/k/v pre-activations (regs)
  xreduce(p.P1, 10, dred, dtot, stM, stI, tid);
  float aq[H], ak[H], av[H];
  {
    float x[H];
#pragma unroll
    for (int j = 0; j < H; ++j)
      x[j] = tanhf(p.g_i[j] * (pre1[j] - stM[j]) * stI[j] + p.be_i[j]);
#pragma unroll
    for (int h = 0; h < H; ++h) { aq[h] = 0.f; ak[h] = 0.f; av[h] = 0.f; }
#pragma unroll
    for (int j = 0; j < H; ++j)
#pragma unroll
      for (int h = 0; h < H; ++h) {
        aq[h] = fmaf(x[j], p.Wq[h * H + j], aq[h]);
        ak[h] = fmaf(x[j], p.Wk[h * H + j], ak[h]);
        av[h] = fmaf(x[j], p.Wv[h * H + j], av[h]);
      }
  }
  __syncthreads();
#pragma unroll
  for (int h = 0; h < H; ++h) {
    float r1 = wred(aq[h]), r2 = wred(aq[h] * aq[h]);
    float r3 = wred(ak[h]), r4 = wred(ak[h] * ak[h]);
    float r5 = wred(av[h]), r6 = wred(av[h] * av[h]);
    if (lane == 0) {
      sredf[wid][h] = r1;      sredf[wid][30 + h] = r2;
      sredf[wid][10 + h] = r3; sredf[wid][40 + h] = r4;
      sredf[wid][20 + h] = r5; sredf[wid][50 + h] = r6;
    }
  }
  __syncthreads();
  if (tid < 60) p.P2[(size_t)k * 60 + tid] = sredf[0][tid] + sredf[1][tid];
  grid.sync();

  // S3: activations + per-block M partials
  xreduce(p.P2, 30, dred, dtot, stM, stI, tid);
  float qv[H], kx[H], vx[H];
#pragma unroll
  for (int h = 0; h < H; ++h) {
    qv[h] = fmaxf(p.g_q[h] * (aq[h] - stM[h])      * stI[h]      + p.be_q[h], 0.f);
    kx[h] = fmaxf(p.g_k[h] * (ak[h] - stM[10 + h]) * stI[10 + h] + p.be_k[h], 0.f);
    vx[h] = tanhf(p.g_v[h] * (av[h] - stM[20 + h]) * stI[20 + h] + p.be_v[h]);
  }
  __syncthreads();
#pragma unroll
  for (int i = 0; i < H; ++i)
#pragma unroll
    for (int j = 0; j < H; ++j) {
      float r = wred(kx[i] * vx[j]);
      if (lane == 0) sredf[wid][i * H + j] = r;
    }
  __syncthreads();
  if (tid < 100) p.Mpart[(size_t)k * 100 + tid] = sredf[0][tid] + sredf[1][tid];
  grid.sync();

  // S4: N = (M Wc^T)/H, prec = q . N
  if (tid < 100) {
    float s = 0.f;
#pragma unroll
    for (int ch = 0; ch < 8; ++ch)
      s += p.Mpart[(size_t)(b * 8 + ch) * 100 + tid];
    Ms[tid] = s;
  }
  __syncthreads();
  if (tid < 100) {
    int i = tid / 10, h = tid % 10;
    float a = 0.f;
#pragma unroll
    for (int j = 0; j < H; ++j) a = fmaf(Ms[i * 10 + j], p.Wc[h * H + j], a);
    Nl[tid] = a * 0.1f;
  }
  __syncthreads();
  float prec[H];
#pragma unroll
  for (int h = 0; h < H; ++h) {
    float a = 0.f;
#pragma unroll
    for (int i = 0; i < H; ++i) a = fmaf(qv[i], Nl[i * 10 + h], a);
    prec[h] = a;
  }
#pragma unroll
  for (int h = 0; h < H; ++h) {
    float r1 = wred(prec[h]), r2 = wred(prec[h] * prec[h]);
    if (lane == 0) { sredf[wid][h] = r1; sredf[wid][10 + h] = r2; }
  }
  __syncthreads();
  if (tid < 20) p.P3[(size_t)k * 20 + tid] = sredf[0][tid] + sredf[1][tid];
  grid.sync();

  // S5: bn+relu, input currents (stride-10), g table
  xreduce(p.P3, 10, dred, dtot, stM, stI, tid);
  {
    float xc[H], Ii[H];
#pragma unroll
    for (int j = 0; j < H; ++j)
      xc[j] = fmaxf(p.g_c[j] * (prec[j] - stM[j]) * stI[j] + p.be_c[j], 0.f);
#pragma unroll
    for (int h = 0; h < H; ++h) {
      float a = 0.f;
#pragma unroll
      for (int j = 0; j < H; ++j) a = fmaf(xc[j], p.W_in[h * H + j], a);
      Ii[h] = a;
    }
    write_iin(p.Iin, b, t, Ii);
    write_g(p.g, (k << 7) | tid);
  }
}

// ======================= scan kernel (both paths) =======================
__global__ __launch_bounds__(128) void k_scan(const float* __restrict__ Iin,
    const float* __restrict__ gw, const float* __restrict__ W_rec,
    const float* __restrict__ W_cls, const float* __restrict__ b_cls,
    float* __restrict__ out) {
  __shared__ __align__(16) float slab[T * 10];   // 40 KB
  __shared__ __align__(16) float gtab[T];        // 4 KB  (total 44 KB < 64 KB)
  const int bb = blockIdx.x, tid = threadIdx.x;
  {
    const float4* src = (const float4*)(Iin + (size_t)bb * (T * 10));
    float4* dst = (float4*)slab;
    for (int i = tid; i < T * 10 / 4; i += 128) dst[i] = src[i];
    for (int i = tid; i < T; i += 128) gtab[i] = gw[i];
  }
  __syncthreads();
  if (tid < 64) {
    const int lane = tid;
    float gs = 0.f;
#pragma unroll
    for (int i = 0; i < 16; ++i) gs += gtab[lane + 64 * i];
    float gtot = __shfl(wred(gs), 0, 64);

    const int slot = lane < H ? lane : 0;   // inactive lanes broadcast slot 0
    float wr[H];
#pragma unroll
    for (int j = 0; j < H; ++j)
      wr[j] = (lane < H) ? W_rec[lane * H + j] : 0.f;

    float cur = 0.f, vm = 0.f, S = 0.f;
    unsigned zm = 0u;

    auto step = [&](float iin, float gt) {
      float p01 = (((zm >> 0) & 1u) ? wr[0] : 0.f) + (((zm >> 1) & 1u) ? wr[1] : 0.f);
      float p23 = (((zm >> 2) & 1u) ? wr[2] : 0.f) + (((zm >> 3) & 1u) ? wr[3] : 0.f);
      float p45 = (((zm >> 4) & 1u) ? wr[4] : 0.f) + (((zm >> 5) & 1u) ? wr[5] : 0.f);
      float p67 = (((zm >> 6) & 1u) ? wr[6] : 0.f) + (((zm >> 7) & 1u) ? wr[7] : 0.f);
      float p89 = (((zm >> 8) & 1u) ? wr[8] : 0.f) + (((zm >> 9) & 1u) ? wr[9] : 0.f);
      float rec = ((p01 + p23) + (p45 + p67)) + p89;
      float i_jump = (cur + iin) + rec;
      float v_dec = fmaf(0.1f, i_jump - vm, vm);  // vm + 0.1*(i_jump - vm)
      cur = 0.8f * i_jump;                        // i_dec
      bool z = v_dec > 0.5f;
      vm = z ? 0.f : v_dec;
      S += z ? gt : 0.f;
      zm = (unsigned)__ballot(z) & 0x3FFu;
    };

    float ibuf[8];
#pragma unroll
    for (int u = 0; u < 8; ++u) ibuf[u] = slab[u * 10 + slot];
    float4 gA = *(const float4*)&gtab[0], gB = *(const float4*)&gtab[4];

    for (int t8 = 0; t8 < T - 8; t8 += 8) {
      float4 nA = *(const float4*)&gtab[t8 + 8];
      float4 nB = *(const float4*)&gtab[t8 + 12];
      step(ibuf[0], gA.x); ibuf[0] = slab[(t8 +  8) * 10 + slot];
      step(ibuf[1], gA.y); ibuf[1] = slab[(t8 +  9) * 10 + slot];
      step(ibuf[2], gA.z); ibuf[2] = slab[(t8 + 10) * 10 + slot];
      step(ibuf[3], gA.w); ibuf[3] = slab[(t8 + 11) * 10 + slot];
      step(ibuf[4], gB.x); ibuf[4] = slab[(t8 + 12) * 10 + slot];
      step(ibuf[5], gB.y); ibuf[5] = slab[(t8 + 13) * 10 + slot];
      step(ibuf[6], gB.z); ibuf[6] = slab[(t8 + 14) * 10 + slot];
      step(ibuf[7], gB.w); ibuf[7] = slab[(t8 + 15) * 10 + slot];
      gA = nA; gB = nB;
    }
    step(ibuf[0], gA.x); step(ibuf[1], gA.y);
    step(ibuf[2], gA.z); step(ibuf[3], gA.w);
    step(ibuf[4], gB.x); step(ibuf[5], gB.y);
    step(ibuf[6], gB.z); step(ibuf[7], gB.w);

    int li = lane < H ? lane : 0;
    float c0 = (lane < H) ? S * W_cls[li]     : 0.f;
    float c1 = (lane < H) ? S * W_cls[H + li] : 0.f;
    float r0 = wred(c0), r1 = wred(c1);
    if (lane == 0) {
      out[bb * 2 + 0] = r0 + gtot * b_cls[0];
      out[bb * 2 + 1] = r1 + gtot * b_cls[1];
    }
  }
}

// ======================= fallback kernels (round-1, verified) =======================
__global__ __launch_bounds__(256) void k_embed(const float* __restrict__ beeg,
    const float* __restrict__ W_ef, const float* __restrict__ b_ef,
    float* __restrict__ pre1) {
  __shared__ float wl[H * C];
  for (int i = threadIdx.x; i < H * C; i += 256) wl[i] = W_ef[i];
  __syncthreads();
  int gid = blockIdx.x * 256 + threadIdx.x;
  int b = gid >> 10, t = gid & 1023;
  float acc[H];
#pragma unroll
  for (int h = 0; h < H; ++h) acc[h] = b_ef[h];
  for (int c = 0; c < C; ++c) {
    float x = beeg[(size_t)(b * C + c) * T + t];
#pragma unroll
    for (int h = 0; h < H; ++h) acc[h] = fmaf(x, wl[h * C + c], acc[h]);
  }
#pragma unroll
  for (int h = 0; h < H; ++h) pre1[(size_t)(b * H + h) * T + t] = acc[h];
}

__global__ __launch_bounds__(256) void k_stats(const float* __restrict__ X,
    float* __restrict__ st) {
  int tensor = blockIdx.x / 10, h = blockIdx.x % 10;
  const float* Xp = X + (size_t)tensor * BHT;
  double s = 0.0, sq = 0.0;
  for (int bb = 0; bb < B; ++bb) {
    const float* row = Xp + (size_t)(bb * H + h) * T;
    for (int t = threadIdx.x; t < T; t += 256) {
      double v = (double)row[t];
      s += v; sq += v * v;
    }
  }
  __shared__ double ls[256], lq[256];
  ls[threadIdx.x] = s; lq[threadIdx.x] = sq;
  __syncthreads();
  for (int off = 128; off; off >>= 1) {
    if (threadIdx.x < off) {
      ls[threadIdx.x] += ls[threadIdx.x + off];
      lq[threadIdx.x] += lq[threadIdx.x + off];
    }
    __syncthreads();
  }
  if (threadIdx.x == 0) {
    double mean = ls[0] / (double)(B * T);
    double var  = lq[0] / (double)(B * T) - mean * mean;
    float* o = st + (size_t)tensor * 32;
    o[h]      = (float)mean;
    o[16 + h] = (float)(1.0 / sqrt(var + 1e-5));
  }
}

__global__ __launch_bounds__(256) void k_qkv_pre(const float* __restrict__ pre1,
    const float* __restrict__ st1, const float* __restrict__ g_i,
    const float* __restrict__ be_i, const float* __restrict__ Wq,
    const float* __restrict__ Wk, const float* __restrict__ Wv,
    float* __restrict__ preq, float* __restrict__ prek, float* __restrict__ prev) {
  int gid = blockIdx.x * 256 + threadIdx.x;
  int b = gid >> 10, t = gid & 1023;
  float x[H];
#pragma unroll
  for (int j = 0; j < H; ++j) {
    float p = pre1[(size_t)(b * H + j) * T + t];
    x[j] = tanhf(g_i[j] * (p - st1[j]) * st1[16 + j] + be_i[j]);
  }
  float aq[H], ak[H], av_[H];
#pragma unroll
  for (int h = 0; h < H; ++h) { aq[h] = 0.f; ak[h] = 0.f; av_[h] = 0.f; }
#pragma unroll
  for (int j = 0; j < H; ++j)
#pragma unroll
    for (int h = 0; h < H; ++h) {
      aq[h]  = fmaf(x[j], Wq[h * H + j], aq[h]);
      ak[h]  = fmaf(x[j], Wk[h * H + j], ak[h]);
      av_[h] = fmaf(x[j], Wv[h * H + j], av_[h]);
    }
#pragma unroll
  for (int h = 0; h < H; ++h) {
    size_t o = (size_t)(b * H + h) * T + t;
    preq[o] = aq[h]; prek[o] = ak[h]; prev[o] = av_[h];
  }
}

__global__ __launch_bounds__(256) void k_act_M(const float* __restrict__ preq,
    const float* __restrict__ prek, const float* __restrict__ prev,
    const float* __restrict__ stq, const float* __restrict__ stk,
    const float* __restrict__ stv,
    const float* __restrict__ g_q, const float* __restrict__ be_q,
    const float* __restrict__ g_k, const float* __restrict__ be_k,
    const float* __restrict__ g_v, const float* __restrict__ be_v,
    float* __restrict__ qout, float* __restrict__ Mpart) {
  int bid = blockIdx.x;
  int b = bid >> 2, chunk = bid & 3;
  int t = chunk * 256 + threadIdx.x;
  float kx[H], vx[H];
#pragma unroll
  for (int h = 0; h < H; ++h) {
    size_t o = (size_t)(b * H + h) * T + t;
    float pq = preq[o], pk = prek[o], pv = prev[o];
    float qv = fmaxf(g_q[h] * (pq - stq[h]) * stq[16 + h] + be_q[h], 0.f);
    qout[o] = qv;
    kx[h] = fmaxf(g_k[h] * (pk - stk[h]) * stk[16 + h] + be_k[h], 0.f);
    vx[h] = tanhf(g_v[h] * (pv - stv[h]) * stv[16 + h] + be_v[h]);
  }
  float m[H * H];
#pragma unroll
  for (int i = 0; i < H; ++i)
#pragma unroll
    for (int j = 0; j < H; ++j) m[i * H + j] = kx[i] * vx[j];
#pragma unroll
  for (int e = 0; e < H * H; ++e)
    for (int off = 32; off; off >>= 1) m[e] += __shfl_down(m[e], off, 64);
  __shared__ float red[4][H * H];
  int wave = threadIdx.x >> 6, lane = threadIdx.x & 63;
  if (lane == 0) {
#pragma unroll
    for (int e = 0; e < H * H; ++e) red[wave][e] = m[e];
  }
  __syncthreads();
  if (threadIdx.x < H * H) {
    Mpart[(size_t)bid * 100 + threadIdx.x] = red[0][threadIdx.x] +
        red[1][threadIdx.x] + red[2][threadIdx.x] + red[3][threadIdx.x];
  }
}

__global__ __launch_bounds__(256) void k_prec(const float* __restrict__ q,
    const float* __restrict__ Mpart, const float* __restrict__ Wc,
    float* __restrict__ prec) {
  int bid = blockIdx.x; int b = bid >> 2, chunk = bid & 3;
  __shared__ float Ms[H * H], Nl[H * H];
  if (threadIdx.x < H * H) {
    float s = 0.f;
#pragma unroll
    for (int c = 0; c < 4; ++c) s += Mpart[(size_t)(b * 4 + c) * 100 + threadIdx.x];
    Ms[threadIdx.x] = s;
  }
  __syncthreads();
  if (threadIdx.x < H * H) {
    int i = threadIdx.x / H, h = threadIdx.x % H;
    float a = 0.f;
#pragma unroll
    for (int j = 0; j < H; ++j) a = fmaf(Ms[i * H + j], Wc[h * H + j], a);
    Nl[threadIdx.x] = a * 0.1f;
  }
  __syncthreads();
  int t = chunk * 256 + threadIdx.x;
  float qv[H];
#pragma unroll
  for (int i = 0; i < H; ++i) qv[i] = q[(size_t)(b * H + i) * T + t];
#pragma unroll
  for (int h = 0; h < H; ++h) {
    float a = 0.f;
#pragma unroll
    for (int i = 0; i < H; ++i) a = fmaf(qv[i], Nl[i * H + h], a);
    prec[(size_t)(b * H + h) * T + t] = a;
  }
}

__global__ __launch_bounds__(256) void k_xc_iin(const float* __restrict__ prec,
    const float* __restrict__ stc, const float* __restrict__ g_c,
    const float* __restrict__ be_c, const float* __restrict__ W_in,
    float* __restrict__ Iin, float* __restrict__ g) {
  int gid = blockIdx.x * 256 + threadIdx.x;
  int b = gid >> 10, t = gid & 1023;
  float xc[H], Ii[H];
#pragma unroll
  for (int j = 0; j < H; ++j) {
    float p = prec[(size_t)(b * H + j) * T + t];
    xc[j] = fmaxf(g_c[j] * (p - stc[j]) * stc[16 + j] + be_c[j], 0.f);
  }
#pragma unroll
  for (int h = 0; h < H; ++h) {
    float a = 0.f;
#pragma unroll
    for (int j = 0; j < H; ++j) a = fmaf(xc[j], W_in[h * H + j], a);
    Ii[h] = a;
  }
  write_iin(Iin, b, t, Ii);
  write_g(g, gid);
}

extern "C" void kernel_launch(void* const* d_in, const int* in_sizes, int n_in,
                              void* d_out, int out_size, void* d_ws, size_t ws_size,
                              hipStream_t stream) {
  const float* beeg  = (const float*)d_in[2];
  const float* W_ef  = (const float*)d_in[4];
  const float* b_ef  = (const float*)d_in[5];
  const float* g_i   = (const float*)d_in[6];
  const float* be_i  = (const float*)d_in[7];
  const float* Wq    = (const float*)d_in[8];
  const float* g_q   = (const float*)d_in[9];
  const float* be_q  = (const float*)d_in[10];
  const float* Wk    = (const float*)d_in[11];
  const float* g_k   = (const float*)d_in[12];
  const float* be_k  = (const float*)d_in[13];
  const float* Wv    = (const float*)d_in[14];
  const float* g_v   = (const float*)d_in[15];
  const float* be_v  = (const float*)d_in[16];
  const float* Wc    = (const float*)d_in[17];
  const float* g_c   = (const float*)d_in[18];
  const float* be_c  = (const float*)d_in[19];
  const float* W_in  = (const float*)d_in[20];
  const float* W_rec = (const float*)d_in[21];
  const float* W_cls = (const float*)d_in[22];
  const float* b_cls = (const float*)d_in[23];

  float* ws  = (float*)d_ws;
  float* Iin = ws + OFF_IIN;
  float* g   = ws + OFF_G;

  Params p;
  p.beeg = beeg; p.W_ef = W_ef; p.b_ef = b_ef; p.g_i = g_i; p.be_i = be_i;
  p.Wq = Wq; p.g_q = g_q; p.be_q = be_q; p.Wk = Wk; p.g_k = g_k; p.be_k = be_k;
  p.Wv = Wv; p.g_v = g_v; p.be_v = be_v; p.Wc = Wc; p.g_c = g_c; p.be_c = be_c;
  p.W_in = W_in;
  p.Iin = Iin; p.g = g;
  p.Mpart = ws + OFF_CMP; p.P1 = ws + OFF_CP1;
  p.P2 = ws + OFF_CP2;    p.P3 = ws + OFF_CP3;

  void* args[] = {&p};
  hipError_t e = hipLaunchCooperativeKernel((void*)fused, dim3(NB), dim3(NT),
                                            args, 0, stream);
  if (e != hipSuccess) {
    (void)hipGetLastError();  // clear sticky error, run fallback pipeline
    float* pre1 = ws + OFF_PRE1;
    float* preq = ws + OFF_PREQ;
    float* prek = ws + OFF_PREK;
    float* prev = ws + OFF_PREV;
    float* q    = ws + OFF_Q;
    float* prec = ws + OFF_PRE1;   // reuse
    float* st1  = ws + OFF_ST1;
    float* stq  = ws + OFF_STQ;
    float* stk  = ws + OFF_STK;
    float* stv  = ws + OFF_STV;
    float* stc  = ws + OFF_STC;
    float* Mp   = ws + OFF_MPF;

    k_embed<<<128, 256, 0, stream>>>(beeg, W_ef, b_ef, pre1);
    k_stats<<<10, 256, 0, stream>>>(pre1, st1);
    k_qkv_pre<<<128, 256, 0, stream>>>(pre1, st1, g_i, be_i, Wq, Wk, Wv,
                                       preq, prek, prev);
    k_stats<<<30, 256, 0, stream>>>(preq, stq);
    k_act_M<<<128, 256, 0, stream>>>(preq, prek, prev, stq, stk, stv,
                                     g_q, be_q, g_k, be_k, g_v, be_v, q, Mp);
    k_prec<<<128, 256, 0, stream>>>(q, Mp, Wc, prec);
    k_stats<<<10, 256, 0, stream>>>(prec, stc);
    k_xc_iin<<<128, 256, 0, stream>>>(prec, stc, g_c, be_c, W_in, Iin, g);
  }
  k_scan<<<B, 128, 0, stream>>>(Iin, g, W_rec, W_cls, b_cls, (float*)d_out);
}

// Round 4
// 330.666 us; speedup vs baseline: 1.2577x; 1.2577x over previous
//
#include <hip/hip_runtime.h>
#include <math.h>

// Model: B=32, C=64, T=1024, H=10, OUT=2.
// ONE kernel, 32 blocks (one per batch element) x 1024 threads (one per t).
// Stages: S1 embed | S2 bn+tanh+qkv | S3 act + per-b M=KV^T (block-local!) |
// S4 N=M Wc^T/H, prec=q.N | S5 bn+relu -> Iin straight into LDS | S6 LSNN
// scan on wave 0 from LDS with ballot spike broadcast + analytic LI weights.
// Only cross-block dependency: BN batch stats (3x) -> tiny f64 partial
// exchange via agent-scope atomics + a 32-block atomic barrier (~2-3us each,
// vs ~35us per CG grid.sync measured in R3: fused=151us @ VALUBusy 2%).
// 32 blocks <= 256 CUs => co-residency guaranteed; no cooperative launch.

constexpr int B = 32, C = 64, T = 1024, H = 10;

struct Params {
  const float *beeg, *W_ef, *b_ef, *g_i, *be_i, *Wq, *g_q, *be_q, *Wk, *g_k,
      *be_k, *Wv, *g_v, *be_v, *Wc, *g_c, *be_c, *W_in, *W_rec, *W_cls, *b_cls;
  int* cnt;            // barrier counters (memset 0 each launch)
  double *P1, *P2, *P3;  // cross-block stat partials
  float* out;
};

__device__ inline float wred(float v) {
#pragma unroll
  for (int o = 32; o; o >>= 1) v += __shfl_down(v, o, 64);
  return v;
}

// 32-block device-scope barrier. Partials are written with agent-scope
// atomic stores before arriving; release/acquire on the counter orders them.
__device__ inline void gbar(int* cnt, int phase, int tid) {
  __syncthreads();
  if (tid == 0) {
    __threadfence();
    __hip_atomic_fetch_add(&cnt[phase], 1, __ATOMIC_RELEASE,
                           __HIP_MEMORY_SCOPE_AGENT);
    while (__hip_atomic_load(&cnt[phase], __ATOMIC_ACQUIRE,
                             __HIP_MEMORY_SCOPE_AGENT) < B)
      __builtin_amdgcn_s_sleep(1);
    __threadfence();
  }
  __syncthreads();
}

__global__ __launch_bounds__(1024) void fused2(Params p) {
  const int b = blockIdx.x, tid = threadIdx.x;
  const int lane = tid & 63, wid = tid >> 6;   // 16 waves
  const int t = tid;

  __shared__ __align__(16) float slab[T * 11];   // 45056 B: scratch then Iin
  __shared__ __align__(16) float gtab[T];        // 4 KB
  __shared__ double dtot[60];
  __shared__ float stM[30], stI[30], Ms[100], Nl[100];

  float* swred = slab;          // [16][60] stats scratch (dead before S5)
  float* wl    = slab + 1024;   // W_ef staging (640)
  float* mpw   = slab + 2048;   // [16][50] M partials

  // ---------------- S1: embed
  for (int i = tid; i < H * C; i += 1024) wl[i] = p.W_ef[i];
  __syncthreads();
  float pre1[H];
#pragma unroll
  for (int h = 0; h < H; ++h) pre1[h] = p.b_ef[h];
  {
    const float* bp = p.beeg + (size_t)b * C * T + t;
    for (int c = 0; c < C; ++c) {
      float x = bp[(size_t)c * T];
#pragma unroll
      for (int h = 0; h < H; ++h) pre1[h] = fmaf(x, wl[h * C + c], pre1[h]);
    }
  }
  // stats-1
#pragma unroll
  for (int h = 0; h < H; ++h) {
    float r1 = wred(pre1[h]), r2 = wred(pre1[h] * pre1[h]);
    if (lane == 0) { swred[wid * 60 + h] = r1; swred[wid * 60 + 10 + h] = r2; }
  }
  __syncthreads();
  if (tid < 20) {
    double s = 0.0;
#pragma unroll
    for (int w = 0; w < 16; ++w) s += (double)swred[w * 60 + tid];
    __hip_atomic_store(&p.P1[b * 20 + tid], s, __ATOMIC_RELAXED,
                       __HIP_MEMORY_SCOPE_AGENT);
  }
  gbar(p.cnt, 0, tid);
  if (tid < 20) {
    double s = 0.0;
    for (int i = 0; i < B; ++i)
      s += __hip_atomic_load(&p.P1[i * 20 + tid], __ATOMIC_RELAXED,
                             __HIP_MEMORY_SCOPE_AGENT);
    dtot[tid] = s;
  }
  __syncthreads();
  if (tid < 10) {
    double mean = dtot[tid] * (1.0 / 32768.0);
    double var  = dtot[10 + tid] * (1.0 / 32768.0) - mean * mean;
    stM[tid] = (float)mean;
    stI[tid] = (float)(1.0 / sqrt(var + 1e-5));
  }
  __syncthreads();

  // ---------------- S2: bn+tanh, q/k/v pre-activations (regs)
  float aq[H], ak[H], av[H];
  {
    float x[H];
#pragma unroll
    for (int j = 0; j < H; ++j)
      x[j] = tanhf(p.g_i[j] * (pre1[j] - stM[j]) * stI[j] + p.be_i[j]);
#pragma unroll
    for (int h = 0; h < H; ++h) { aq[h] = 0.f; ak[h] = 0.f; av[h] = 0.f; }
#pragma unroll
    for (int j = 0; j < H; ++j)
#pragma unroll
      for (int h = 0; h < H; ++h) {
        aq[h] = fmaf(x[j], p.Wq[h * H + j], aq[h]);
        ak[h] = fmaf(x[j], p.Wk[h * H + j], ak[h]);
        av[h] = fmaf(x[j], p.Wv[h * H + j], av[h]);
      }
  }
  __syncthreads();   // swred reuse
#pragma unroll
  for (int h = 0; h < H; ++h) {
    float r1 = wred(aq[h]), r2 = wred(aq[h] * aq[h]);
    float r3 = wred(ak[h]), r4 = wred(ak[h] * ak[h]);
    float r5 = wred(av[h]), r6 = wred(av[h] * av[h]);
    if (lane == 0) {
      swred[wid * 60 + h]      = r1; swred[wid * 60 + 30 + h] = r2;
      swred[wid * 60 + 10 + h] = r3; swred[wid * 60 + 40 + h] = r4;
      swred[wid * 60 + 20 + h] = r5; swred[wid * 60 + 50 + h] = r6;
    }
  }
  __syncthreads();
  if (tid < 60) {
    double s = 0.0;
#pragma unroll
    for (int w = 0; w < 16; ++w) s += (double)swred[w * 60 + tid];
    __hip_atomic_store(&p.P2[b * 60 + tid], s, __ATOMIC_RELAXED,
                       __HIP_MEMORY_SCOPE_AGENT);
  }
  gbar(p.cnt, 1, tid);
  if (tid < 60) {
    double s = 0.0;
    for (int i = 0; i < B; ++i)
      s += __hip_atomic_load(&p.P2[i * 60 + tid], __ATOMIC_RELAXED,
                             __HIP_MEMORY_SCOPE_AGENT);
    dtot[tid] = s;
  }
  __syncthreads();
  if (tid < 30) {
    double mean = dtot[tid] * (1.0 / 32768.0);
    double var  = dtot[30 + tid] * (1.0 / 32768.0) - mean * mean;
    stM[tid] = (float)mean;
    stI[tid] = (float)(1.0 / sqrt(var + 1e-5));
  }
  __syncthreads();

  // ---------------- S3: activations + per-b M (block-local reduction)
  float qv[H], kx[H], vx[H];
#pragma unroll
  for (int h = 0; h < H; ++h) {
    qv[h] = fmaxf(p.g_q[h] * (aq[h] - stM[h])      * stI[h]      + p.be_q[h], 0.f);
    kx[h] = fmaxf(p.g_k[h] * (ak[h] - stM[10 + h]) * stI[10 + h] + p.be_k[h], 0.f);
    vx[h] = tanhf(p.g_v[h] * (av[h] - stM[20 + h]) * stI[20 + h] + p.be_v[h]);
  }
  __syncthreads();   // mpw region reuse
  for (int pass = 0; pass < 2; ++pass) {
#pragma unroll
    for (int i = 0; i < 5; ++i)
#pragma unroll
      for (int j = 0; j < H; ++j) {
        float r = wred(kx[pass * 5 + i] * vx[j]);
        if (lane == 0) mpw[wid * 50 + i * 10 + j] = r;
      }
    __syncthreads();
    if (tid < 50) {
      float s = 0.f;
#pragma unroll
      for (int w = 0; w < 16; ++w) s += mpw[w * 50 + tid];
      Ms[pass * 50 + tid] = s;
    }
    __syncthreads();
  }

  // ---------------- S4: N = (M Wc^T)/H, prec = q . N
  if (tid < 100) {
    int i = tid / 10, h = tid % 10;
    float a = 0.f;
#pragma unroll
    for (int j = 0; j < H; ++j) a = fmaf(Ms[i * 10 + j], p.Wc[h * H + j], a);
    Nl[tid] = a * 0.1f;
  }
  __syncthreads();
  float prec[H];
#pragma unroll
  for (int h = 0; h < H; ++h) {
    float a = 0.f;
#pragma unroll
    for (int i = 0; i < H; ++i) a = fmaf(qv[i], Nl[i * 10 + h], a);
    prec[h] = a;
  }
#pragma unroll
  for (int h = 0; h < H; ++h) {
    float r1 = wred(prec[h]), r2 = wred(prec[h] * prec[h]);
    if (lane == 0) { swred[wid * 60 + h] = r1; swred[wid * 60 + 10 + h] = r2; }
  }
  __syncthreads();
  if (tid < 20) {
    double s = 0.0;
#pragma unroll
    for (int w = 0; w < 16; ++w) s += (double)swred[w * 60 + tid];
    __hip_atomic_store(&p.P3[b * 20 + tid], s, __ATOMIC_RELAXED,
                       __HIP_MEMORY_SCOPE_AGENT);
  }
  gbar(p.cnt, 2, tid);
  if (tid < 20) {
    double s = 0.0;
    for (int i = 0; i < B; ++i)
      s += __hip_atomic_load(&p.P3[i * 20 + tid], __ATOMIC_RELAXED,
                             __HIP_MEMORY_SCOPE_AGENT);
    dtot[tid] = s;
  }
  __syncthreads();
  if (tid < 10) {
    double mean = dtot[tid] * (1.0 / 32768.0);
    double var  = dtot[10 + tid] * (1.0 / 32768.0) - mean * mean;
    stM[tid] = (float)mean;
    stI[tid] = (float)(1.0 / sqrt(var + 1e-5));
  }
  __syncthreads();   // also: all slab-scratch reads done before S5 overwrites

  // ---------------- S5: bn+relu, Iin straight into LDS slab (stride 11)
  {
    float xc[H], Ii[H];
#pragma unroll
    for (int j = 0; j < H; ++j)
      xc[j] = fmaxf(p.g_c[j] * (prec[j] - stM[j]) * stI[j] + p.be_c[j], 0.f);
#pragma unroll
    for (int h = 0; h < H; ++h) {
      float a = 0.f;
#pragma unroll
      for (int j = 0; j < H; ++j) a = fmaf(xc[j], p.W_in[h * H + j], a);
      Ii[h] = a;
    }
#pragma unroll
    for (int h = 0; h < H; ++h) slab[t * 11 + h] = Ii[h];
    {  // analytic LI readout weight g[t]
      const double a_ = 0.9, d_ = 0.8, c_ = 0.1;
      int Mi = T - 1 - t;
      double Ga = a_ * (1.0 - pow(a_, (double)(Mi + 1))) / (1.0 - a_);
      double Gd = d_ * (1.0 - pow(d_, (double)(Mi + 1))) / (1.0 - d_);
      gtab[t] = (float)(c_ * (Ga - Gd) / (a_ - d_) / (double)T);
    }
  }
  __syncthreads();

  // ---------------- S6: LSNN scan, wave 0 only, from LDS
  if (tid < 64) {
    float gs = 0.f;
#pragma unroll
    for (int i = 0; i < 16; ++i) gs += gtab[lane + 64 * i];
    float gtot = __shfl(wred(gs), 0, 64);

    const int slot = lane < H ? lane : 0;   // inactive lanes broadcast slot 0
    float wr[H];
#pragma unroll
    for (int j = 0; j < H; ++j)
      wr[j] = (lane < H) ? p.W_rec[lane * H + j] : 0.f;

    float cur = 0.f, vm = 0.f, S = 0.f;
    unsigned zm = 0u;

    auto step = [&](float iin, float gt) {
      float p01 = (((zm >> 0) & 1u) ? wr[0] : 0.f) + (((zm >> 1) & 1u) ? wr[1] : 0.f);
      float p23 = (((zm >> 2) & 1u) ? wr[2] : 0.f) + (((zm >> 3) & 1u) ? wr[3] : 0.f);
      float p45 = (((zm >> 4) & 1u) ? wr[4] : 0.f) + (((zm >> 5) & 1u) ? wr[5] : 0.f);
      float p67 = (((zm >> 6) & 1u) ? wr[6] : 0.f) + (((zm >> 7) & 1u) ? wr[7] : 0.f);
      float p89 = (((zm >> 8) & 1u) ? wr[8] : 0.f) + (((zm >> 9) & 1u) ? wr[9] : 0.f);
      float rec = ((p01 + p23) + (p45 + p67)) + p89;
      float i_jump = (cur + iin) + rec;
      float v_dec = fmaf(0.1f, i_jump - vm, vm);  // vm + 0.1*(i_jump - vm)
      cur = 0.8f * i_jump;                        // i_dec
      bool z = v_dec > 0.5f;
      vm = z ? 0.f : v_dec;
      S += z ? gt : 0.f;
      zm = (unsigned)__ballot(z) & 0x3FFu;
    };

    float ibuf[8];
#pragma unroll
    for (int u = 0; u < 8; ++u) ibuf[u] = slab[u * 11 + slot];
    float4 gA = *(const float4*)&gtab[0], gB = *(const float4*)&gtab[4];

    for (int t8 = 0; t8 < T - 8; t8 += 8) {
      float4 nA = *(const float4*)&gtab[t8 + 8];
      float4 nB = *(const float4*)&gtab[t8 + 12];
      step(ibuf[0], gA.x); ibuf[0] = slab[(t8 +  8) * 11 + slot];
      step(ibuf[1], gA.y); ibuf[1] = slab[(t8 +  9) * 11 + slot];
      step(ibuf[2], gA.z); ibuf[2] = slab[(t8 + 10) * 11 + slot];
      step(ibuf[3], gA.w); ibuf[3] = slab[(t8 + 11) * 11 + slot];
      step(ibuf[4], gB.x); ibuf[4] = slab[(t8 + 12) * 11 + slot];
      step(ibuf[5], gB.y); ibuf[5] = slab[(t8 + 13) * 11 + slot];
      step(ibuf[6], gB.z); ibuf[6] = slab[(t8 + 14) * 11 + slot];
      step(ibuf[7], gB.w); ibuf[7] = slab[(t8 + 15) * 11 + slot];
      gA = nA; gB = nB;
    }
    step(ibuf[0], gA.x); step(ibuf[1], gA.y);
    step(ibuf[2], gA.z); step(ibuf[3], gA.w);
    step(ibuf[4], gB.x); step(ibuf[5], gB.y);
    step(ibuf[6], gB.z); step(ibuf[7], gB.w);

    int li = lane < H ? lane : 0;
    float c0 = (lane < H) ? S * p.W_cls[li]     : 0.f;
    float c1 = (lane < H) ? S * p.W_cls[H + li] : 0.f;
    float r0 = wred(c0), r1 = wred(c1);
    if (lane == 0) {
      p.out[b * 2 + 0] = r0 + gtot * p.b_cls[0];
      p.out[b * 2 + 1] = r1 + gtot * p.b_cls[1];
    }
  }
}

extern "C" void kernel_launch(void* const* d_in, const int* in_sizes, int n_in,
                              void* d_out, int out_size, void* d_ws, size_t ws_size,
                              hipStream_t stream) {
  Params p;
  p.beeg  = (const float*)d_in[2];
  p.W_ef  = (const float*)d_in[4];
  p.b_ef  = (const float*)d_in[5];
  p.g_i   = (const float*)d_in[6];
  p.be_i  = (const float*)d_in[7];
  p.Wq    = (const float*)d_in[8];
  p.g_q   = (const float*)d_in[9];
  p.be_q  = (const float*)d_in[10];
  p.Wk    = (const float*)d_in[11];
  p.g_k   = (const float*)d_in[12];
  p.be_k  = (const float*)d_in[13];
  p.Wv    = (const float*)d_in[14];
  p.g_v   = (const float*)d_in[15];
  p.be_v  = (const float*)d_in[16];
  p.Wc    = (const float*)d_in[17];
  p.g_c   = (const float*)d_in[18];
  p.be_c  = (const float*)d_in[19];
  p.W_in  = (const float*)d_in[20];
  p.W_rec = (const float*)d_in[21];
  p.W_cls = (const float*)d_in[22];
  p.b_cls = (const float*)d_in[23];

  char* ws = (char*)d_ws;
  p.cnt = (int*)ws;                       // 3 counters, memset below
  p.P1  = (double*)(ws + 256);            // 32*20 doubles
  p.P2  = (double*)(ws + 256 + 5120);     // 32*60 doubles
  p.P3  = (double*)(ws + 256 + 5120 + 15360);  // 32*20 doubles
  p.out = (float*)d_out;

  hipMemsetAsync(d_ws, 0, 256, stream);   // zero barrier counters (capturable)
  fused2<<<dim3(B), dim3(1024), 0, stream>>>(p);
}